// Round 1
// baseline (239.748 us; speedup 1.0000x reference)
//
#include <hip/hip_runtime.h>

// NumericalBiasModule: out[e] = b2 + W2 · relu(W1 · rel(x[src], x[dst]) + b1)
// rel = [ratio | log_ratio | abs_diff | rel_diff], 128 features.
//
// Round-18 change: 32-edge tiles via mfma_f32_32x32x16_bf16 (was 16-edge /
// 16x16x32). Gather bytes/edge and decode VALU/edge unchanged; per edge this
// HALVES: LDS weight ds_read_b128 (20 per 32 edges, was 20 per 16 -> LDS pipe
// ~38% -> ~19%), MFMA issue slots, index loads, loop overhead. MFMA pipe
// cycles -15% (8.07cyc/32x32x16 vs 2x4.85 for the 16x16 pair, m119).
// Depth-2 gather slots dropped (r17 measured +1%); the 8 up-front loads/tile
// provide equivalent per-wave MLP at lower VGPR.
//
// Geometry: lane r=lane&31 = edge-in-tile (A row), h=lane>>5 = k-half.
// A-frag[j] = feat[r][h*8+j] (k16 slice). B: col=lane&31, same k grouping.
// C/D (m74/m101 verified): col=lane&31 (hid), row=(reg&3)+8*(reg>>2)+4*h.
// Slice s (k=s*16..s*16+15) maps to node chunk 2s+h (dims s*16+h*8..+7).
// Epilogue: 32-lane hid reduce = row_ror 1/2/4/8 + row_bcast15 (rows 1,3
// hold full sums), cndmask tree routes pp[l] -> out row (l&3)+8*(l>>2)+4h.
//
// Packed node record (validated r16): per 8-dim chunk 32B = xh bf16[8] |
// xl8 u8[8] mantissa ext | lu8 u8[8] log-quant; 128B/node (precision-forced:
// ratio needs ~16-bit mantissa, log needs 8 bits -> 32 bits/dim).

#define DD    32
#define HID   64
#define RELF  128
#define EPSF  1e-8f
#define LXLO  -18.420681f          // log(1e-8)
#define LXSC  13.843137f           // 255 / 18.420681
#define LXIV  0.07223796f          // 18.420681 / 255
#define MSC   3.0517578125e-05f    // 2^-15

typedef short  bf16x8 __attribute__((ext_vector_type(8)));
typedef float  f32x4  __attribute__((ext_vector_type(4)));
typedef float  f32x16 __attribute__((ext_vector_type(16)));

union U8 { unsigned u[4]; bf16x8 v; uint4 q4; };
union Q  { uint4 v; unsigned u[4]; float f[4]; };

static __device__ __forceinline__ unsigned pk_tr(float lo, float hi) {
    return __builtin_amdgcn_perm(__builtin_bit_cast(unsigned, hi),
                                 __builtin_bit_cast(unsigned, lo), 0x07060302u);
}
static __device__ __forceinline__ unsigned rne_bits(float f) {
    unsigned u = __builtin_bit_cast(unsigned, f);
    return u + 0x7fffu + ((u >> 16) & 1u);
}
static __device__ __forceinline__ unsigned pk_rne(float lo, float hi) {
    return __builtin_amdgcn_perm(rne_bits(hi), rne_bits(lo), 0x07060302u);
}
static __device__ __forceinline__ float hi_f32(float f) {
    return __builtin_bit_cast(float, __builtin_bit_cast(unsigned, f) & 0xffff0000u);
}
static __device__ __forceinline__ float ubyte(unsigned w, int b) {
    return (float)((w >> (8 * b)) & 0xffu);   // folds to v_cvt_f32_ubyteN
}
static __device__ __forceinline__ unsigned q8(float v) {
    int u = (int)(v + 0.5f);
    return (unsigned)(u > 255 ? 255 : (u < 0 ? 0 : u));
}
// pp += dpp(pp): VALU-pipe cross-lane add. 0x121/2/4/8 = row_ror:N (16-lane),
// 0x142 = row_bcast15 (lane15->row1, lane47->row3; rows 0,2 get +0).
template <int CTRL>
static __device__ __forceinline__ float dpp_ror_add(float pp) {
    int s = __builtin_bit_cast(int, pp);
    int t = __builtin_amdgcn_update_dpp(0, s, CTRL, 0xf, 0xf, true);
    return pp + __builtin_bit_cast(float, t);
}

// ---- prep: one thread per (node, q) 8-dim chunk ----
__global__ __launch_bounds__(256)
void prep_pack(const float* __restrict__ x, uint4* __restrict__ rec, int nchunk)
{
    int i = blockIdx.x * blockDim.x + threadIdx.x;   // chunk = node*4 + q
    if (i >= nchunk) return;
    const float4* xp = (const float4*)(x + (size_t)i * 8);
    float4 v0 = xp[0], v1 = xp[1];
    float xv[8] = {v0.x, v0.y, v0.z, v0.w, v1.x, v1.y, v1.z, v1.w};

    unsigned xh[4];
    #pragma unroll
    for (int p = 0; p < 4; ++p) xh[p] = pk_tr(xv[2*p], xv[2*p+1]);

    unsigned xl[2] = {0u, 0u}, lu[2] = {0u, 0u};
    #pragma unroll
    for (int e = 0; e < 8; ++e) {
        float a  = xv[e];
        float ah = hi_f32(a);
        float f  = 0.f;
        if (ah > 0.f)
            f = (a * __builtin_amdgcn_rcpf(ah) - 1.f) * 32768.f;   // 2^15
        xl[e >> 2] |= q8(f) << (8 * (e & 3));
        float lxe = __logf(a + EPSF);
        lu[e >> 2] |= q8((lxe - LXLO) * LXSC) << (8 * (e & 3));
    }

    uint4 r0; r0.x = xh[0]; r0.y = xh[1]; r0.z = xh[2]; r0.w = xh[3];
    uint4 r1; r1.x = xl[0]; r1.y = xl[1]; r1.z = lu[0]; r1.w = lu[1];
    rec[2 * i]     = r0;
    rec[2 * i + 1] = r1;
}

// PACK=1: packed records (2 lines/edge-side). PACK=0: raw x + per-edge logf.
template <int PACK>
__global__ __launch_bounds__(256, 4)
void edge_bias_mfma(const float* __restrict__ x,
                    const int*   __restrict__ ei,     // [2, E]
                    const float* __restrict__ W1,     // [64, 128]
                    const float* __restrict__ b1,
                    const float* __restrict__ W2,
                    const float* __restrict__ b2,
                    const uint4* __restrict__ rec,    // [N, 8] packed
                    float* __restrict__ out,
                    int E)
{
    const int lane = threadIdx.x & 63;
    const int wv   = threadIdx.x >> 6;
    const int wave = (blockIdx.x * blockDim.x + threadIdx.x) >> 6;
    const int nwv  = (gridDim.x * blockDim.x) >> 6;
    const int r = lane & 31;      // edge-in-tile (A row) / hid col (B,C)
    const int h = lane >> 5;      // k-half

    // ---- LDS weight image: 5 sets x 2 col-tiles x 2 k16-slices = 20 x 1KB ----
    // sets: 0=W0h (ratio hi)  1=W0l (ratio lo)  2=WL (log)  3=WA  4=WD
    __shared__ uint4 sW[20 * 64];
    for (int f = wv; f < 20; f += 4) {
        const int set = f >> 2, ct = (f >> 1) & 1, sl = f & 1;
        const int fb  = (set <= 1) ? 0 : (set - 1) * 32;   // 0,0,32,64,96
        const float* wr = W1 + (ct * 32 + r) * RELF + fb + sl * 16 + h * 8;
        U8 tw;
        if (set == 0) {
            #pragma unroll
            for (int p = 0; p < 4; ++p) tw.u[p] = pk_tr(wr[2*p], wr[2*p+1]);
        } else if (set == 1) {
            #pragma unroll
            for (int p = 0; p < 4; ++p) {
                float w0 = wr[2*p], w1 = wr[2*p+1];
                tw.u[p] = pk_rne(w0 - hi_f32(w0), w1 - hi_f32(w1));
            }
        } else {
            #pragma unroll
            for (int p = 0; p < 4; ++p) tw.u[p] = pk_rne(wr[2*p], wr[2*p+1]);
        }
        sW[f * 64 + lane] = tw.q4;
    }
    __syncthreads();

    float b1v[2], w2v[2];
    #pragma unroll
    for (int ct = 0; ct < 2; ++ct) {
        b1v[ct] = b1[ct * 32 + r];
        w2v[ct] = W2[ct * 32 + r];
    }
    const float b2s = b2[0];

    // decode one packed 8-dim chunk -> 8 fp32 x + bf16 log A-frag slice
    auto decode = [&](const Q& hq, const Q& mq, float* xv, bf16x8& lfrag) {
        #pragma unroll
        for (int p = 0; p < 4; ++p) {
            float lo = __builtin_bit_cast(float, hq.u[p] << 16);
            float hi = __builtin_bit_cast(float, hq.u[p] & 0xffff0000u);
            unsigned xb = (p < 2) ? mq.u[0] : mq.u[1];
            float m0 = ubyte(xb, (2 * p) & 3);
            float m1 = ubyte(xb, (2 * p + 1) & 3);
            xv[2 * p]     = fmaf(lo * MSC, m0, lo);
            xv[2 * p + 1] = fmaf(hi * MSC, m1, hi);
        }
        U8 L;
        #pragma unroll
        for (int p = 0; p < 4; ++p) {
            unsigned lb = (p < 2) ? mq.u[2] : mq.u[3];
            float l0 = fmaf(ubyte(lb, (2 * p) & 3),     LXIV, LXLO);
            float l1 = fmaf(ubyte(lb, (2 * p + 1) & 3), LXIV, LXLO);
            L.u[p] = pk_tr(l0, l1);   // truncate: lx already quantized at 0.036
        }
        lfrag = L.v;
    };

    const int ntiles = (E + 31) >> 5;
    for (int t = wave; t < ntiles; t += nwv) {
        int em = (t << 5) + r; if (em > E - 1) em = E - 1;
        const int sn = ei[em], dn = ei[E + em];

        // ---- gather: lane (r,h) reads chunks {h, 2+h} of each side ----
        Q hi0, mi0, hi1, mi1, hj0, mj0, hj1, mj1;
        if constexpr (PACK) {
            const uint4* pi = rec + (size_t)sn * 8 + (h << 1);
            const uint4* pj = rec + (size_t)dn * 8 + (h << 1);
            hi0.v = pi[0]; mi0.v = pi[1]; hi1.v = pi[4]; mi1.v = pi[5];
            hj0.v = pj[0]; mj0.v = pj[1]; hj1.v = pj[4]; mj1.v = pj[5];
        } else {
            const uint4* pi = (const uint4*)(x + (size_t)sn * DD + h * 8);
            const uint4* pj = (const uint4*)(x + (size_t)dn * DD + h * 8);
            hi0.v = pi[0]; mi0.v = pi[1]; hi1.v = pi[4]; mi1.v = pi[5];
            hj0.v = pj[0]; mj0.v = pj[1]; hj1.v = pj[4]; mj1.v = pj[5];
        }

        // opaque offset: stops LICM hoisting weight ds_reads into registers
        int off = lane;
        asm volatile("" : "+v"(off));
        auto ldfrag = [&](int set, int ct, int sl) {
            U8 w; w.q4 = sW[(set * 4 + ct * 2 + sl) * 64 + off];
            return w.v;
        };

        f32x16 acc0, acc1;
        #pragma unroll
        for (int i = 0; i < 16; ++i) { acc0[i] = b1v[0]; acc1[i] = b1v[1]; }

        #pragma unroll
        for (int sl = 0; sl < 2; ++sl) {
            const Q& hI = sl ? hi1 : hi0;  const Q& mI = sl ? mi1 : mi0;
            const Q& hJ = sl ? hj1 : hj0;  const Q& mJ = sl ? mj1 : mj0;

            float xiv[8], xjv[8];
            bf16x8 aLi, aLj;
            if constexpr (PACK) {
                decode(hI, mI, xiv, aLi);
                decode(hJ, mJ, xjv, aLj);
            } else {
                #pragma unroll
                for (int p = 0; p < 4; ++p) {
                    xiv[p] = hI.f[p]; xiv[4 + p] = mI.f[p];
                    xjv[p] = hJ.f[p]; xjv[4 + p] = mJ.f[p];
                }
                U8 ti, tj;
                #pragma unroll
                for (int p = 0; p < 4; ++p) {
                    ti.u[p] = pk_rne(__logf(xiv[2*p] + EPSF), __logf(xiv[2*p+1] + EPSF));
                    tj.u[p] = pk_rne(__logf(xjv[2*p] + EPSF), __logf(xjv[2*p+1] + EPSF));
                }
                aLi = ti.v; aLj = tj.v;
            }
            // -lxj: bf16 sign flip on the A side (replaces a WLn weight set)
            U8 nj; nj.v = aLj;
            #pragma unroll
            for (int p = 0; p < 4; ++p) nj.u[p] ^= 0x80008000u;

            U8 R, Rl, Aa, Dd;
            #pragma unroll
            for (int p = 0; p < 4; ++p) {
                float a0 = xiv[2*p], a1 = xiv[2*p+1];
                float c0 = xjv[2*p], c1 = xjv[2*p+1];
                float r0 = a0 * __builtin_amdgcn_rcpf(c0 + EPSF);
                float r1 = a1 * __builtin_amdgcn_rcpf(c1 + EPSF);
                float d0 = fabsf(a0 - c0), d1 = fabsf(a1 - c1);
                float g0 = d0 * __builtin_amdgcn_rcpf(fmaxf(a0, c0) + EPSF);
                float g1 = d1 * __builtin_amdgcn_rcpf(fmaxf(a1, c1) + EPSF);
                R.u[p]  = pk_tr(r0, r1);
                Rl.u[p] = pk_tr(r0 - hi_f32(r0), r1 - hi_f32(r1));
                Aa.u[p] = pk_tr(d0, d1);
                Dd.u[p] = pk_tr(g0, g1);
            }

            #pragma unroll
            for (int ct = 0; ct < 2; ++ct) {
                bf16x8 fW0h = ldfrag(0, ct, sl);
                bf16x8 fW0l = ldfrag(1, ct, sl);
                bf16x8 fWL  = ldfrag(2, ct, sl);
                bf16x8 fWA  = ldfrag(3, ct, sl);
                bf16x8 fWD  = ldfrag(4, ct, sl);
                if (ct == 0) {
                    acc0 = __builtin_amdgcn_mfma_f32_32x32x16_bf16(R.v,  fW0h, acc0, 0, 0, 0);
                    acc0 = __builtin_amdgcn_mfma_f32_32x32x16_bf16(Rl.v, fW0h, acc0, 0, 0, 0);
                    acc0 = __builtin_amdgcn_mfma_f32_32x32x16_bf16(R.v,  fW0l, acc0, 0, 0, 0);
                    acc0 = __builtin_amdgcn_mfma_f32_32x32x16_bf16(aLi,  fWL,  acc0, 0, 0, 0);
                    acc0 = __builtin_amdgcn_mfma_f32_32x32x16_bf16(nj.v, fWL,  acc0, 0, 0, 0);
                    acc0 = __builtin_amdgcn_mfma_f32_32x32x16_bf16(Aa.v, fWA,  acc0, 0, 0, 0);
                    acc0 = __builtin_amdgcn_mfma_f32_32x32x16_bf16(Dd.v, fWD,  acc0, 0, 0, 0);
                } else {
                    acc1 = __builtin_amdgcn_mfma_f32_32x32x16_bf16(R.v,  fW0h, acc1, 0, 0, 0);
                    acc1 = __builtin_amdgcn_mfma_f32_32x32x16_bf16(Rl.v, fW0h, acc1, 0, 0, 0);
                    acc1 = __builtin_amdgcn_mfma_f32_32x32x16_bf16(R.v,  fW0l, acc1, 0, 0, 0);
                    acc1 = __builtin_amdgcn_mfma_f32_32x32x16_bf16(aLi,  fWL,  acc1, 0, 0, 0);
                    acc1 = __builtin_amdgcn_mfma_f32_32x32x16_bf16(nj.v, fWL,  acc1, 0, 0, 0);
                    acc1 = __builtin_amdgcn_mfma_f32_32x32x16_bf16(Aa.v, fWA,  acc1, 0, 0, 0);
                    acc1 = __builtin_amdgcn_mfma_f32_32x32x16_bf16(Dd.v, fWD,  acc1, 0, 0, 0);
                }
            }
        }

        // ---- layer 2 + 32-lane hid reduce (DPP, VALU pipe) ----
        float pp[16];
        #pragma unroll
        for (int g = 0; g < 16; ++g) {
            float v0 = fmaxf(acc0[g], 0.f), v1 = fmaxf(acc1[g], 0.f);
            pp[g] = fmaf(v0, w2v[0], v1 * w2v[1]);
        }
        #pragma unroll
        for (int g = 0; g < 16; ++g) {
            float s = pp[g];
            s = dpp_ror_add<0x121>(s);   // row_ror:1
            s = dpp_ror_add<0x122>(s);   // row_ror:2
            s = dpp_ror_add<0x124>(s);   // row_ror:4
            s = dpp_ror_add<0x128>(s);   // row_ror:8  -> each 16-row has its sum
            s = dpp_ror_add<0x142>(s);   // row_bcast15 -> rows 1,3 hold 32-lane sum
            pp[g] = s;
        }
        // rows 1,3 (lanes 16-31, 48-63) write: lane l=lane&15 stores pp[l]
        // at row (l&3)+8*(l>>2)+4h  (C/D row map inverse, bijective onto 0..31)
        if ((lane >> 4) & 1) {
            const int l = lane & 15;
            float q8a[8], q4a[4], q2a[2];
            #pragma unroll
            for (int i = 0; i < 8; ++i) q8a[i] = (l & 1) ? pp[2*i+1] : pp[2*i];
            #pragma unroll
            for (int i = 0; i < 4; ++i) q4a[i] = (l & 2) ? q8a[2*i+1] : q8a[2*i];
            #pragma unroll
            for (int i = 0; i < 2; ++i) q2a[i] = (l & 4) ? q4a[2*i+1] : q4a[2*i];
            float v = (l & 8) ? q2a[1] : q2a[0];
            const int e2 = (t << 5) + (l & 3) + ((l >> 2) << 3) + (h << 2);
            if (e2 < E) out[e2] = v + b2s;
        }
    }
}

extern "C" void kernel_launch(void* const* d_in, const int* in_sizes, int n_in,
                              void* d_out, int out_size, void* d_ws, size_t ws_size,
                              hipStream_t stream)
{
    const float* x   = (const float*)d_in[0];
    const int*   ei  = (const int*)  d_in[1];
    const float* W1  = (const float*)d_in[2];
    const float* b1  = (const float*)d_in[3];
    const float* W2  = (const float*)d_in[4];
    const float* b2  = (const float*)d_in[5];
    float* out = (float*)d_out;

    const int E  = out_size;       // 1,000,000
    const int Nd = in_sizes[0];    // N*D = 3,200,000
    uint4* rec = (uint4*)d_ws;     // N * 128 bytes = Nd * 4 bytes

    // grid: 1954 blocks = 7816 waves; 31250 tiles -> 7802 waves do 4 tiles,
    // 14 do 3 (kills the 7-vs-8 tail imbalance of the old 2048-block grid).
    const int blocks = 1954;

    const bool pack = ws_size >= (size_t)Nd * 4 && (Nd % 8) == 0;
    if (pack) {
        const int nchunk = Nd / 8;
        prep_pack<<<(nchunk + 255) / 256, 256, 0, stream>>>(x, rec, nchunk);
        edge_bias_mfma<1><<<blocks, 256, 0, stream>>>(x, ei, W1, b1, W2, b2, rec, out, E);
    } else {
        edge_bias_mfma<0><<<blocks, 256, 0, stream>>>(x, ei, W1, b1, W2, b2, rec, out, E);
    }
}

// Round 3
// 138.864 us; speedup vs baseline: 1.7265x; 1.7265x over previous
//
#include <hip/hip_runtime.h>

// NumericalBiasModule: out[e] = b2 + W2 · relu(W1 · rel(x[src], x[dst]) + b1)
// rel = [ratio | log_ratio | abs_diff | rel_diff], 128 features.
//
// Round-20 = round-19 resubmit (container infra failure, zero data).
// 32-edge tiles via mfma_f32_32x32x16_bf16 (r18 concept), spill fix.
// r18 regressed 66->181us: WRITE_SIZE 3.9MB->235MB = scratch spill of the
// pp[16] epilogue array + cndmask tree under the (256,4) 128-VGPR cap
// (~7.5KB/tile x 31250 tiles matches the 235MB). Changes vs r18:
//   1. epilogue: per-g DPP reduce + conditional 2-lane store (no pp[16],
//      no routing tree) -- only ~2 live temps.
//   2. __launch_bounds__(256,3): VGPR cap ~170. Measured occupancy in the
//      good runs was ~35% ~= 11 waves/CU ~= 3 waves/SIMD already.
//
// Geometry (validated r18, absmax 2.0 pass): lane r=lane&31 = edge (A row),
// h=lane>>5 = k-half. Slice sl covers k=sl*16..+15 = node chunk 2sl+h.
// C/D: col=lane&31 (hid), row=(reg&3)+8*(reg>>2)+4h (edge).
// Epilogue: row_ror 1/2/4/8 (16-lane sum in all lanes) + row_bcast15
// (rows 1,3 get the 32-lane sum); lanes 16+g / 48+g store edge
// (g&3)+8*(g>>2)+4h -- bijective onto 0..31.
//
// Packed node record (validated r16): per 8-dim chunk 32B = xh bf16[8] |
// xl8 u8[8] mantissa ext | lu8 u8[8] log-quant; 128B/node (precision-forced).

#define DD    32
#define HID   64
#define RELF  128
#define EPSF  1e-8f
#define LXLO  -18.420681f          // log(1e-8)
#define LXSC  13.843137f           // 255 / 18.420681
#define LXIV  0.07223796f          // 18.420681 / 255
#define MSC   3.0517578125e-05f    // 2^-15

typedef short  bf16x8 __attribute__((ext_vector_type(8)));
typedef float  f32x16 __attribute__((ext_vector_type(16)));

union U8 { unsigned u[4]; bf16x8 v; uint4 q4; };
union Q  { uint4 v; unsigned u[4]; float f[4]; };

static __device__ __forceinline__ unsigned pk_tr(float lo, float hi) {
    return __builtin_amdgcn_perm(__builtin_bit_cast(unsigned, hi),
                                 __builtin_bit_cast(unsigned, lo), 0x07060302u);
}
static __device__ __forceinline__ unsigned rne_bits(float f) {
    unsigned u = __builtin_bit_cast(unsigned, f);
    return u + 0x7fffu + ((u >> 16) & 1u);
}
static __device__ __forceinline__ unsigned pk_rne(float lo, float hi) {
    return __builtin_amdgcn_perm(rne_bits(hi), rne_bits(lo), 0x07060302u);
}
static __device__ __forceinline__ float hi_f32(float f) {
    return __builtin_bit_cast(float, __builtin_bit_cast(unsigned, f) & 0xffff0000u);
}
static __device__ __forceinline__ float ubyte(unsigned w, int b) {
    return (float)((w >> (8 * b)) & 0xffu);   // folds to v_cvt_f32_ubyteN
}
static __device__ __forceinline__ unsigned q8(float v) {
    int u = (int)(v + 0.5f);
    return (unsigned)(u > 255 ? 255 : (u < 0 ? 0 : u));
}
// pp += dpp(pp): VALU-pipe cross-lane add. 0x121/2/4/8 = row_ror:N (16-lane),
// 0x142 = row_bcast15 (lane15->row1, lane47->row3; rows 0,2 add 0).
template <int CTRL>
static __device__ __forceinline__ float dpp_ror_add(float pp) {
    int s = __builtin_bit_cast(int, pp);
    int t = __builtin_amdgcn_update_dpp(0, s, CTRL, 0xf, 0xf, true);
    return pp + __builtin_bit_cast(float, t);
}

// ---- prep: one thread per (node, q) 8-dim chunk ----
__global__ __launch_bounds__(256)
void prep_pack(const float* __restrict__ x, uint4* __restrict__ rec, int nchunk)
{
    int i = blockIdx.x * blockDim.x + threadIdx.x;   // chunk = node*4 + q
    if (i >= nchunk) return;
    const float4* xp = (const float4*)(x + (size_t)i * 8);
    float4 v0 = xp[0], v1 = xp[1];
    float xv[8] = {v0.x, v0.y, v0.z, v0.w, v1.x, v1.y, v1.z, v1.w};

    unsigned xh[4];
    #pragma unroll
    for (int p = 0; p < 4; ++p) xh[p] = pk_tr(xv[2*p], xv[2*p+1]);

    unsigned xl[2] = {0u, 0u}, lu[2] = {0u, 0u};
    #pragma unroll
    for (int e = 0; e < 8; ++e) {
        float a  = xv[e];
        float ah = hi_f32(a);
        float f  = 0.f;
        if (ah > 0.f)
            f = (a * __builtin_amdgcn_rcpf(ah) - 1.f) * 32768.f;   // 2^15
        xl[e >> 2] |= q8(f) << (8 * (e & 3));
        float lxe = __logf(a + EPSF);
        lu[e >> 2] |= q8((lxe - LXLO) * LXSC) << (8 * (e & 3));
    }

    uint4 r0; r0.x = xh[0]; r0.y = xh[1]; r0.z = xh[2]; r0.w = xh[3];
    uint4 r1; r1.x = xl[0]; r1.y = xl[1]; r1.z = lu[0]; r1.w = lu[1];
    rec[2 * i]     = r0;
    rec[2 * i + 1] = r1;
}

// PACK=1: packed records (2 lines/edge-side). PACK=0: raw x + per-edge logf.
template <int PACK>
__global__ __launch_bounds__(256, 3)
void edge_bias_mfma(const float* __restrict__ x,
                    const int*   __restrict__ ei,     // [2, E]
                    const float* __restrict__ W1,     // [64, 128]
                    const float* __restrict__ b1,
                    const float* __restrict__ W2,
                    const float* __restrict__ b2,
                    const uint4* __restrict__ rec,    // [N, 8] packed
                    float* __restrict__ out,
                    int E)
{
    const int lane = threadIdx.x & 63;
    const int wv   = threadIdx.x >> 6;
    const int wave = (blockIdx.x * blockDim.x + threadIdx.x) >> 6;
    const int nwv  = (gridDim.x * blockDim.x) >> 6;
    const int r = lane & 31;      // edge-in-tile (A row) / hid col (B,C)
    const int h = lane >> 5;      // k-half

    // ---- LDS weight image: 5 sets x 2 col-tiles x 2 k16-slices = 20 x 1KB ----
    // sets: 0=W0h (ratio hi)  1=W0l (ratio lo)  2=WL (log)  3=WA  4=WD
    __shared__ uint4 sW[20 * 64];
    for (int f = wv; f < 20; f += 4) {
        const int set = f >> 2, ct = (f >> 1) & 1, sl = f & 1;
        const int fb  = (set <= 1) ? 0 : (set - 1) * 32;   // 0,0,32,64,96
        const float* wr = W1 + (ct * 32 + r) * RELF + fb + sl * 16 + h * 8;
        U8 tw;
        if (set == 0) {
            #pragma unroll
            for (int p = 0; p < 4; ++p) tw.u[p] = pk_tr(wr[2*p], wr[2*p+1]);
        } else if (set == 1) {
            #pragma unroll
            for (int p = 0; p < 4; ++p) {
                float w0 = wr[2*p], w1 = wr[2*p+1];
                tw.u[p] = pk_rne(w0 - hi_f32(w0), w1 - hi_f32(w1));
            }
        } else {
            #pragma unroll
            for (int p = 0; p < 4; ++p) tw.u[p] = pk_rne(wr[2*p], wr[2*p+1]);
        }
        sW[f * 64 + lane] = tw.q4;
    }
    __syncthreads();

    float b1v[2], w2v[2];
    #pragma unroll
    for (int ct = 0; ct < 2; ++ct) {
        b1v[ct] = b1[ct * 32 + r];
        w2v[ct] = W2[ct * 32 + r];
    }
    const float b2s = b2[0];

    // decode one packed 8-dim chunk -> 8 fp32 x + bf16 log A-frag slice
    auto decode = [&](const Q& hq, const Q& mq, float* xv, bf16x8& lfrag) {
        #pragma unroll
        for (int p = 0; p < 4; ++p) {
            float lo = __builtin_bit_cast(float, hq.u[p] << 16);
            float hi = __builtin_bit_cast(float, hq.u[p] & 0xffff0000u);
            unsigned xb = (p < 2) ? mq.u[0] : mq.u[1];
            float m0 = ubyte(xb, (2 * p) & 3);
            float m1 = ubyte(xb, (2 * p + 1) & 3);
            xv[2 * p]     = fmaf(lo * MSC, m0, lo);
            xv[2 * p + 1] = fmaf(hi * MSC, m1, hi);
        }
        U8 L;
        #pragma unroll
        for (int p = 0; p < 4; ++p) {
            unsigned lb = (p < 2) ? mq.u[2] : mq.u[3];
            float l0 = fmaf(ubyte(lb, (2 * p) & 3),     LXIV, LXLO);
            float l1 = fmaf(ubyte(lb, (2 * p + 1) & 3), LXIV, LXLO);
            L.u[p] = pk_tr(l0, l1);   // truncate: lx already quantized at 0.036
        }
        lfrag = L.v;
    };

    const int ntiles = (E + 31) >> 5;
    for (int t = wave; t < ntiles; t += nwv) {
        int em = (t << 5) + r; if (em > E - 1) em = E - 1;
        const int sn = ei[em], dn = ei[E + em];

        // ---- gather: lane (r,h) reads chunks {h, 2+h} of each side ----
        Q hi0, mi0, hi1, mi1, hj0, mj0, hj1, mj1;
        if constexpr (PACK) {
            const uint4* pi = rec + (size_t)sn * 8 + (h << 1);
            const uint4* pj = rec + (size_t)dn * 8 + (h << 1);
            hi0.v = pi[0]; mi0.v = pi[1]; hi1.v = pi[4]; mi1.v = pi[5];
            hj0.v = pj[0]; mj0.v = pj[1]; hj1.v = pj[4]; mj1.v = pj[5];
        } else {
            const uint4* pi = (const uint4*)(x + (size_t)sn * DD + h * 8);
            const uint4* pj = (const uint4*)(x + (size_t)dn * DD + h * 8);
            hi0.v = pi[0]; mi0.v = pi[1]; hi1.v = pi[4]; mi1.v = pi[5];
            hj0.v = pj[0]; mj0.v = pj[1]; hj1.v = pj[4]; mj1.v = pj[5];
        }

        // opaque offset: stops LICM hoisting weight ds_reads into registers
        int off = lane;
        asm volatile("" : "+v"(off));
        auto ldfrag = [&](int set, int ct, int sl) {
            U8 w; w.q4 = sW[(set * 4 + ct * 2 + sl) * 64 + off];
            return w.v;
        };

        f32x16 acc0, acc1;
        #pragma unroll
        for (int i = 0; i < 16; ++i) { acc0[i] = b1v[0]; acc1[i] = b1v[1]; }

        #pragma unroll
        for (int sl = 0; sl < 2; ++sl) {
            const Q& hI = sl ? hi1 : hi0;  const Q& mI = sl ? mi1 : mi0;
            const Q& hJ = sl ? hj1 : hj0;  const Q& mJ = sl ? mj1 : mj0;

            float xiv[8], xjv[8];
            bf16x8 aLi, aLj;
            if constexpr (PACK) {
                decode(hI, mI, xiv, aLi);
                decode(hJ, mJ, xjv, aLj);
            } else {
                #pragma unroll
                for (int p = 0; p < 4; ++p) {
                    xiv[p] = hI.f[p]; xiv[4 + p] = mI.f[p];
                    xjv[p] = hJ.f[p]; xjv[4 + p] = mJ.f[p];
                }
                U8 ti, tj;
                #pragma unroll
                for (int p = 0; p < 4; ++p) {
                    ti.u[p] = pk_rne(__logf(xiv[2*p] + EPSF), __logf(xiv[2*p+1] + EPSF));
                    tj.u[p] = pk_rne(__logf(xjv[2*p] + EPSF), __logf(xjv[2*p+1] + EPSF));
                }
                aLi = ti.v; aLj = tj.v;
            }
            // -lxj: bf16 sign flip on the A side (replaces a WLn weight set)
            U8 nj; nj.v = aLj;
            #pragma unroll
            for (int p = 0; p < 4; ++p) nj.u[p] ^= 0x80008000u;

            U8 R, Rl, Aa, Dd;
            #pragma unroll
            for (int p = 0; p < 4; ++p) {
                float a0 = xiv[2*p], a1 = xiv[2*p+1];
                float c0 = xjv[2*p], c1 = xjv[2*p+1];
                float r0 = a0 * __builtin_amdgcn_rcpf(c0 + EPSF);
                float r1 = a1 * __builtin_amdgcn_rcpf(c1 + EPSF);
                float d0 = fabsf(a0 - c0), d1 = fabsf(a1 - c1);
                float g0 = d0 * __builtin_amdgcn_rcpf(fmaxf(a0, c0) + EPSF);
                float g1 = d1 * __builtin_amdgcn_rcpf(fmaxf(a1, c1) + EPSF);
                R.u[p]  = pk_tr(r0, r1);
                Rl.u[p] = pk_tr(r0 - hi_f32(r0), r1 - hi_f32(r1));
                Aa.u[p] = pk_tr(d0, d1);
                Dd.u[p] = pk_tr(g0, g1);
            }

            #pragma unroll
            for (int ct = 0; ct < 2; ++ct) {
                bf16x8 fW0h = ldfrag(0, ct, sl);
                bf16x8 fW0l = ldfrag(1, ct, sl);
                bf16x8 fWL  = ldfrag(2, ct, sl);
                bf16x8 fWA  = ldfrag(3, ct, sl);
                bf16x8 fWD  = ldfrag(4, ct, sl);
                if (ct == 0) {
                    acc0 = __builtin_amdgcn_mfma_f32_32x32x16_bf16(R.v,  fW0h, acc0, 0, 0, 0);
                    acc0 = __builtin_amdgcn_mfma_f32_32x32x16_bf16(Rl.v, fW0h, acc0, 0, 0, 0);
                    acc0 = __builtin_amdgcn_mfma_f32_32x32x16_bf16(R.v,  fW0l, acc0, 0, 0, 0);
                    acc0 = __builtin_amdgcn_mfma_f32_32x32x16_bf16(aLi,  fWL,  acc0, 0, 0, 0);
                    acc0 = __builtin_amdgcn_mfma_f32_32x32x16_bf16(nj.v, fWL,  acc0, 0, 0, 0);
                    acc0 = __builtin_amdgcn_mfma_f32_32x32x16_bf16(Aa.v, fWA,  acc0, 0, 0, 0);
                    acc0 = __builtin_amdgcn_mfma_f32_32x32x16_bf16(Dd.v, fWD,  acc0, 0, 0, 0);
                } else {
                    acc1 = __builtin_amdgcn_mfma_f32_32x32x16_bf16(R.v,  fW0h, acc1, 0, 0, 0);
                    acc1 = __builtin_amdgcn_mfma_f32_32x32x16_bf16(Rl.v, fW0h, acc1, 0, 0, 0);
                    acc1 = __builtin_amdgcn_mfma_f32_32x32x16_bf16(R.v,  fW0l, acc1, 0, 0, 0);
                    acc1 = __builtin_amdgcn_mfma_f32_32x32x16_bf16(aLi,  fWL,  acc1, 0, 0, 0);
                    acc1 = __builtin_amdgcn_mfma_f32_32x32x16_bf16(nj.v, fWL,  acc1, 0, 0, 0);
                    acc1 = __builtin_amdgcn_mfma_f32_32x32x16_bf16(Aa.v, fWA,  acc1, 0, 0, 0);
                    acc1 = __builtin_amdgcn_mfma_f32_32x32x16_bf16(Dd.v, fWD,  acc1, 0, 0, 0);
                }
            }
        }

        // ---- layer 2 + 32-lane hid reduce, one g at a time (no live array) ----
        // After ror 1/2/4/8 every lane in a 16-group holds that group's sum;
        // row_bcast15 folds group 0->1 and 2->3, so rows 1,3 hold the 32-lane
        // sum. Lane 16+g (h=0) and lane 48+g (h=1) store edge
        // (g&3) + 8*(g>>2) + 4h.  Only ~2 temps live -> no spill.
        #pragma unroll
        for (int g = 0; g < 16; ++g) {
            float s = fmaf(fmaxf(acc0[g], 0.f), w2v[0],
                           fmaxf(acc1[g], 0.f) * w2v[1]);
            s = dpp_ror_add<0x121>(s);   // row_ror:1
            s = dpp_ror_add<0x122>(s);   // row_ror:2
            s = dpp_ror_add<0x124>(s);   // row_ror:4
            s = dpp_ror_add<0x128>(s);   // row_ror:8
            s = dpp_ror_add<0x142>(s);   // row_bcast15
            if ((((lane >> 4) & 1) != 0) && (lane & 15) == g) {
                const int e2 = (t << 5) + (g & 3) + ((g >> 2) << 3) + (h << 2);
                if (e2 < E) out[e2] = s + b2s;
            }
        }
    }
}

extern "C" void kernel_launch(void* const* d_in, const int* in_sizes, int n_in,
                              void* d_out, int out_size, void* d_ws, size_t ws_size,
                              hipStream_t stream)
{
    const float* x   = (const float*)d_in[0];
    const int*   ei  = (const int*)  d_in[1];
    const float* W1  = (const float*)d_in[2];
    const float* b1  = (const float*)d_in[3];
    const float* W2  = (const float*)d_in[4];
    const float* b2  = (const float*)d_in[5];
    float* out = (float*)d_out;

    const int E  = out_size;       // 1,000,000
    const int Nd = in_sizes[0];    // N*D = 3,200,000
    uint4* rec = (uint4*)d_ws;     // N * 128 bytes = Nd * 4 bytes

    // 1954 blocks = 7816 waves; 31250 tiles -> ~4 tiles/wave, even tail.
    const int blocks = 1954;

    const bool pack = ws_size >= (size_t)Nd * 4 && (Nd % 8) == 0;
    if (pack) {
        const int nchunk = Nd / 8;
        prep_pack<<<(nchunk + 255) / 256, 256, 0, stream>>>(x, rec, nchunk);
        edge_bias_mfma<1><<<blocks, 256, 0, stream>>>(x, ei, W1, b1, W2, b2, rec, out, E);
    } else {
        edge_bias_mfma<0><<<blocks, 256, 0, stream>>>(x, ei, W1, b1, W2, b2, rec, out, E);
    }
}